// Round 3
// baseline (14191.913 us; speedup 1.0000x reference)
//
#include <hip/hip_runtime.h>

typedef unsigned short ushort_t;
typedef unsigned int   uint32;

#define TP_    68      // padded token count (65 -> 68)
#define HSTR   132     // h_s row stride (padded: bank-conflict-free per-lane row reads)
#define EPS_   1e-5f
#define SCALE_ 0.17677669529663687f  // 1/sqrt(32)

__device__ __forceinline__ float bfu(ushort_t u) {
  union { uint32 i; float f; } c; c.i = ((uint32)u) << 16; return c.f;
}
__device__ __forceinline__ void bf2(uint32 u, float& a, float& b) {
  union { uint32 i; float f; } c0, c1;
  c0.i = u << 16; c1.i = u & 0xffff0000u; a = c0.f; b = c1.f;
}
__device__ __forceinline__ ushort_t f2bf(float f) {
  union { float f; uint32 i; } c; c.f = f;
  uint32 r = c.i + 0x7fffu + ((c.i >> 16) & 1u);
  return (ushort_t)(r >> 16);
}
__device__ __forceinline__ float clamp_s(float s) {
  return fminf(fmaxf(s, -60.f), 60.f);
}

// Statistical dtype sniff on the first 256 ushorts of x.
// bf16 buffer of N(0,1) samples: every ushort has a sane exponent field, ~0 zeros.
// fp32 buffer: even ushorts are raw mantissa bits -> ~37% insane exponent fields
// (>=16 of 128 virtually certain). fp32 buffer holding bf16-rounded values: even
// ushorts are all exactly 0 -> zeros >= 64.
__device__ bool sniff_f32(const ushort_t* x) {
  int insane = 0, zeros = 0;
  for (int i = 0; i < 256; ++i) {
    ushort_t u = x[i];
    int e = (u >> 7) & 0xFF;
    if (u == 0) zeros++;
    else if (e == 0xFF || e < 0x60) insane++;
  }
  return (insane >= 16) || (zeros >= 64);
}

struct WPack {
  const void* src[23];
  unsigned    off[23];
  unsigned    n[23];
};

// Convert all weight arrays to canonical bf16 in ws.
__global__ __launch_bounds__(256) void canon(WPack p, const ushort_t* x, ushort_t* dst) {
  const bool f32 = sniff_f32(x);
  const int gid = blockIdx.x * blockDim.x + threadIdx.x;
  const int gsz = gridDim.x * blockDim.x;
  for (int a = 0; a < 23; ++a) {
    unsigned n = p.n[a];
    ushort_t* d = dst + p.off[a];
    if (f32) {
      const float* s = (const float*)p.src[a];
      for (unsigned i = gid; i < n; i += gsz) d[i] = f2bf(s[i]);
    } else {
      const ushort_t* s = (const ushort_t*)p.src[a];
      for (unsigned i = gid; i < n; i += gsz) d[i] = s[i];
    }
  }
}

__global__ __launch_bounds__(256)
void vit_fused(const ushort_t* __restrict__ x,          // ORIGINAL x (dtype sniffed)
               const ushort_t* __restrict__ patch_w,    // all weights: canonical bf16 in ws
               const ushort_t* __restrict__ patch_b,
               const ushort_t* __restrict__ cls_token,
               const ushort_t* __restrict__ pos_embed,
               const ushort_t* __restrict__ qkv_w,
               const ushort_t* __restrict__ qkv_b,
               const ushort_t* __restrict__ out_w,
               const ushort_t* __restrict__ out_b,
               const ushort_t* __restrict__ ln1_s,
               const ushort_t* __restrict__ ln1_b,
               const ushort_t* __restrict__ ln2_s,
               const ushort_t* __restrict__ ln2_b,
               const ushort_t* __restrict__ ff1_w,
               const ushort_t* __restrict__ ff1_b,
               const ushort_t* __restrict__ ff2_w,
               const ushort_t* __restrict__ ff2_b,
               const ushort_t* __restrict__ qr1_w,
               const ushort_t* __restrict__ qr1_b,
               const ushort_t* __restrict__ qr2_w,
               const ushort_t* __restrict__ qr2_b,
               const ushort_t* __restrict__ q_weights,
               const ushort_t* __restrict__ clf_w,
               const ushort_t* __restrict__ clf_b,
               void* __restrict__ out)
{
  // LDS: 17952 + 17408 + 17408 = 52768 B
  __shared__ __align__(16) ushort_t h_s[TP_ * HSTR];   // hidden state bf16 (4488 dw)
  __shared__ __align__(16) ushort_t kbuf[TP_ * 128];   // k / o^T / ffs / scratch (4352 dw)
  __shared__ __align__(16) ushort_t vbuf[TP_ * 128];   // v / patch_w staging     (4352 dw)

  const int tid  = threadIdx.x;
  const int wid  = tid >> 6;
  const int lane = tid & 63;
  const int b    = blockIdx.x;
  const bool f32m = sniff_f32(x);

  // ---------------- phase 0: stage x + patch_w; zero-init remaining LDS ----------------
  {
    if (f32m) {
      const float* xf = (const float*)x + (size_t)b * 3072;
      for (int i2 = tid; i2 < 1536; i2 += 256) {
        uint32 lo = f2bf(xf[2 * i2]);
        uint32 hi = f2bf(xf[2 * i2 + 1]);
        ((uint32*)kbuf)[i2] = lo | (hi << 16);
      }
    } else {
      const uint32* xb = (const uint32*)x + (size_t)b * 1536;   // 3072 bf16 = 1536 dw
      for (int i2 = tid; i2 < 1536; i2 += 256) ((uint32*)kbuf)[i2] = xb[i2];
    }
    const uint32* pw = (const uint32*)patch_w;                  // 6144 bf16 = 3072 dw
    for (int i2 = tid; i2 < 3072; i2 += 256) ((uint32*)vbuf)[i2] = pw[i2];
    for (int i2 = tid + 1536; i2 < 4352; i2 += 256) ((uint32*)kbuf)[i2] = 0;
    for (int i2 = tid + 3072; i2 < 4352; i2 += 256) ((uint32*)vbuf)[i2] = 0;
    for (int i2 = tid; i2 < 4488; i2 += 256) ((uint32*)h_s)[i2] = 0;
  }
  __syncthreads();

  // patch embed: tok[p][d] = sum_{c,py,qx} x[c][4pi+py][4pj+qx] * pw[d][c][py][qx]
  #pragma unroll 1
  for (int it = 0; it < 32; ++it) {
    int idx = tid + 256 * it;              // 0..8191
    int p = idx >> 7, d = idx & 127;
    int pi = p >> 3, pj = p & 7;
    float acc = 0.f;
    #pragma unroll
    for (int c = 0; c < 3; ++c) {
      #pragma unroll
      for (int py = 0; py < 4; ++py) {
        const uint32* xr = (const uint32*)kbuf + ((c * 1024 + (pi * 4 + py) * 32 + pj * 4) >> 1);
        const uint32* wr = (const uint32*)vbuf + ((d * 48 + c * 16 + py * 4) >> 1);
        #pragma unroll
        for (int q2 = 0; q2 < 2; ++q2) {
          float xa, xb2, wa, wb;
          bf2(xr[q2], xa, xb2); bf2(wr[q2], wa, wb);
          acc += xa * wa + xb2 * wb;
        }
      }
    }
    acc += bfu(patch_b[d]) + bfu(pos_embed[(1 + p) * 128 + d]);
    h_s[(1 + p) * HSTR + d] = f2bf(acc);
  }
  if (tid < 128) {
    h_s[tid] = f2bf(bfu(cls_token[tid]) + bfu(pos_embed[tid]));
    // rows 65..67 stay exactly zero forever (phases B/C skip them)
  }

  // ---------------- transformer layers ----------------
  #pragma unroll 1
  for (int il = 0; il < 4; ++il) {
    __syncthreads();   // h ready; kbuf/vbuf free

    // ---- A1: k,v = h @ Wkv^T + b -> kbuf/vbuf (bf16)
    {
      const uint32* Wkv = (const uint32*)qkv_w + ((size_t)il * 384 + 128) * 64;
      const ushort_t* bkv = qkv_b + il * 384 + 128;
      #pragma unroll 1
      for (int it = 0; it < 17; ++it) {
        int t = wid + 4 * it;
        const uint32* hrow = (const uint32*)h_s + t * 66;
        float a0 = bfu(bkv[lane]);
        float a1 = bfu(bkv[lane + 64]);
        float a2 = bfu(bkv[lane + 128]);
        float a3 = bfu(bkv[lane + 192]);
        #pragma unroll 4
        for (int k2 = 0; k2 < 64; ++k2) {
          float ha, hb, wa, wb;
          bf2(hrow[k2], ha, hb);
          bf2(Wkv[(lane      ) * 64 + k2], wa, wb); a0 += ha * wa + hb * wb;
          bf2(Wkv[(lane + 64 ) * 64 + k2], wa, wb); a1 += ha * wa + hb * wb;
          bf2(Wkv[(lane + 128) * 64 + k2], wa, wb); a2 += ha * wa + hb * wb;
          bf2(Wkv[(lane + 192) * 64 + k2], wa, wb); a3 += ha * wa + hb * wb;
        }
        kbuf[t * 128 + lane]      = f2bf(a0);
        kbuf[t * 128 + lane + 64] = f2bf(a1);
        vbuf[t * 128 + lane]      = f2bf(a2);
        vbuf[t * 128 + lane + 64] = f2bf(a3);
      }
    }
    __syncthreads();   // kv ready

    // ---- A2: attention; head = wid. Rows: r=lane, then r=64 (all lanes redundantly).
    float o0[32], o1[32];
    {
      const uint32* Wq = (const uint32*)qkv_w + (size_t)il * 384 * 64 + (wid * 32) * 64;
      const ushort_t* bq = qkv_b + il * 384 + wid * 32;

      auto attn_row = [&](int r, float* o) {
        float qreg[32];
        #pragma unroll
        for (int d = 0; d < 32; ++d) qreg[d] = bfu(bq[d]);
        const uint32* hrow = (const uint32*)h_s + r * 66;
        #pragma unroll 1
        for (int k2 = 0; k2 < 64; ++k2) {
          float ha, hb; bf2(hrow[k2], ha, hb);
          #pragma unroll
          for (int d = 0; d < 32; ++d) {
            float wa, wb; bf2(Wq[d * 64 + k2], wa, wb);
            qreg[d] += ha * wa + hb * wb;
          }
        }
        float m = -60.f, l = 0.f;
        #pragma unroll 1
        for (int j = 0; j < 65; ++j) {
          const uint32* krow = (const uint32*)kbuf + j * 64 + wid * 16;
          float acc = 0.f;
          #pragma unroll
          for (int d2 = 0; d2 < 16; ++d2) {
            float ka, kb; bf2(krow[d2], ka, kb);
            acc += qreg[2 * d2] * ka + qreg[2 * d2 + 1] * kb;
          }
          float s = clamp_s(acc * SCALE_);
          float nm = fmaxf(m, s);
          l = l * __expf(m - nm) + __expf(s - nm);
          m = nm;
        }
        float linv = 1.0f / l;
        #pragma unroll
        for (int d = 0; d < 32; ++d) o[d] = 0.f;
        #pragma unroll 1
        for (int j = 0; j < 65; ++j) {
          const uint32* krow = (const uint32*)kbuf + j * 64 + wid * 16;
          float acc = 0.f;
          #pragma unroll
          for (int d2 = 0; d2 < 16; ++d2) {
            float ka, kb; bf2(krow[d2], ka, kb);
            acc += qreg[2 * d2] * ka + qreg[2 * d2 + 1] * kb;
          }
          float pj = __expf(clamp_s(acc * SCALE_) - m) * linv;
          const uint32* vrow = (const uint32*)vbuf + j * 64 + wid * 16;
          #pragma unroll
          for (int d2 = 0; d2 < 16; ++d2) {
            float va, vb; bf2(vrow[d2], va, vb);
            o[2 * d2]     += pj * va;
            o[2 * d2 + 1] += pj * vb;
          }
        }
      };
      attn_row(lane, o0);
      attn_row(64, o1);
    }
    __syncthreads();   // kv reads complete -> kbuf reusable as o^T

    #pragma unroll
    for (int d = 0; d < 32; ++d)
      kbuf[(wid * 32 + d) * TP_ + lane] = f2bf(o0[d]);
    if (lane == 0) {
      #pragma unroll
      for (int d = 0; d < 32; ++d)
        kbuf[(wid * 32 + d) * TP_ + 64] = f2bf(o1[d]);
    }
    __syncthreads();   // o^T ready

    // ---- B: out-proj + residual + LN1
    {
      const uint32* Wo = (const uint32*)out_w + (size_t)il * 128 * 64;
      const ushort_t* bo  = out_b + il * 128;
      const ushort_t* g1s = ln1_s + il * 128;
      const ushort_t* g1b = ln1_b + il * 128;
      #pragma unroll 1
      for (int it = 0; it < 17; ++it) {
        int t = wid + 4 * it;
        if (t < 65) {
          float a0 = bfu(bo[lane]);
          float a1 = bfu(bo[lane + 64]);
          const uint32* w0 = Wo + lane * 64;
          const uint32* w1 = Wo + (lane + 64) * 64;
          #pragma unroll 4
          for (int k2 = 0; k2 < 64; ++k2) {
            float c0 = bfu(kbuf[(2 * k2    ) * TP_ + t]);
            float c1 = bfu(kbuf[(2 * k2 + 1) * TP_ + t]);
            float wa, wb; bf2(w0[k2], wa, wb); a0 += c0 * wa + c1 * wb;
            float wc, wd; bf2(w1[k2], wc, wd); a1 += c0 * wc + c1 * wd;
          }
          float x0 = bfu(h_s[t * HSTR + lane])      + a0;
          float x1 = bfu(h_s[t * HSTR + lane + 64]) + a1;
          float s = x0 + x1, ss = x0 * x0 + x1 * x1;
          #pragma unroll
          for (int off = 32; off > 0; off >>= 1) {
            s  += __shfl_xor(s, off);
            ss += __shfl_xor(ss, off);
          }
          float mean = s * (1.f / 128.f);
          float inv  = rsqrtf(fmaxf(ss * (1.f / 128.f) - mean * mean, 0.f) + EPS_);
          float y0 = (x0 - mean) * inv * bfu(g1s[lane])      + bfu(g1b[lane]);
          float y1 = (x1 - mean) * inv * bfu(g1s[lane + 64]) + bfu(g1b[lane + 64]);
          h_s[t * HSTR + lane]      = f2bf(y0);
          h_s[t * HSTR + lane + 64] = f2bf(y1);
        }
      }
    }
    __syncthreads();   // o^T reads done -> kbuf reusable as ffs scratch

    // ---- C: FF (relu) + residual + LN2
    {
      const uint32* W1 = (const uint32*)ff1_w + (size_t)il * 256 * 64;
      const uint32* W2 = (const uint32*)ff2_w + (size_t)il * 128 * 128;
      const ushort_t* bff1 = ff1_b + il * 256;
      const ushort_t* bff2 = ff2_b + il * 128;
      const ushort_t* g2s  = ln2_s + il * 128;
      const ushort_t* g2b  = ln2_b + il * 128;
      float* ffs = (float*)kbuf + wid * 256;   // per-wave private 1KB slice
      #pragma unroll 1
      for (int it = 0; it < 17; ++it) {
        int t = wid + 4 * it;
        bool real = (t < 65);
        if (real) {
          const uint32* hrow = (const uint32*)h_s + t * 66;
          float r0 = bfu(bff1[lane * 4]);
          float r1 = bfu(bff1[lane * 4 + 1]);
          float r2 = bfu(bff1[lane * 4 + 2]);
          float r3 = bfu(bff1[lane * 4 + 3]);
          #pragma unroll 2
          for (int k2 = 0; k2 < 64; ++k2) {
            float ha, hb, wa, wb;
            bf2(hrow[k2], ha, hb);
            bf2(W1[(lane * 4    ) * 64 + k2], wa, wb); r0 += ha * wa + hb * wb;
            bf2(W1[(lane * 4 + 1) * 64 + k2], wa, wb); r1 += ha * wa + hb * wb;
            bf2(W1[(lane * 4 + 2) * 64 + k2], wa, wb); r2 += ha * wa + hb * wb;
            bf2(W1[(lane * 4 + 3) * 64 + k2], wa, wb); r3 += ha * wa + hb * wb;
          }
          float4 rr;
          rr.x = fmaxf(r0, 0.f); rr.y = fmaxf(r1, 0.f);
          rr.z = fmaxf(r2, 0.f); rr.w = fmaxf(r3, 0.f);
          ((float4*)ffs)[lane] = rr;
        }
        __syncthreads();   // uniform
        if (real) {
          float a0 = bfu(bff2[lane]);
          float a1 = bfu(bff2[lane + 64]);
          const uint32* w0 = W2 + lane * 128;
          const uint32* w1 = W2 + (lane + 64) * 128;
          const float2* fv = (const float2*)ffs;
          #pragma unroll 4
          for (int k2 = 0; k2 < 128; ++k2) {
            float2 f = fv[k2];
            float wa, wb; bf2(w0[k2], wa, wb); a0 += f.x * wa + f.y * wb;
            float wc, wd; bf2(w1[k2], wc, wd); a1 += f.x * wc + f.y * wd;
          }
          float x0 = bfu(h_s[t * HSTR + lane])      + a0;
          float x1 = bfu(h_s[t * HSTR + lane + 64]) + a1;
          float s = x0 + x1, ss = x0 * x0 + x1 * x1;
          #pragma unroll
          for (int off = 32; off > 0; off >>= 1) {
            s  += __shfl_xor(s, off);
            ss += __shfl_xor(ss, off);
          }
          float mean = s * (1.f / 128.f);
          float inv  = rsqrtf(fmaxf(ss * (1.f / 128.f) - mean * mean, 0.f) + EPS_);
          float y0 = (x0 - mean) * inv * bfu(g2s[lane])      + bfu(g2b[lane]);
          float y1 = (x1 - mean) * inv * bfu(g2s[lane + 64]) + bfu(g2b[lane + 64]);
          h_s[t * HSTR + lane]      = f2bf(y0);
          h_s[t * HSTR + lane + 64] = f2bf(y1);
        }
      }
    }
  } // layers

  // ---------------- head ----------------
  __syncthreads();
  float* scr = (float*)kbuf;
  {
    int j = tid & 31;
    const uint32* hrow0 = (const uint32*)h_s;
    const uint32* w = (const uint32*)qr1_w + j * 64;
    float acc = 0.f;
    #pragma unroll 4
    for (int k2 = 0; k2 < 64; ++k2) {
      float ha, hb, wa, wb;
      bf2(hrow0[k2], ha, hb); bf2(w[k2], wa, wb);
      acc += ha * wa + hb * wb;
    }
    float u = fmaxf(acc + bfu(qr1_b[j]), 0.f);
    if (tid < 32) scr[tid] = u;
  }
  __syncthreads();
  if (tid < 10) {
    float qo[4]; float cp = 1.f;
    #pragma unroll
    for (int j2 = 0; j2 < 4; ++j2) {
      float acc = 0.f;
      #pragma unroll
      for (int k = 0; k < 32; ++k) acc += scr[k] * bfu(qr2_w[j2 * 32 + k]);
      float qin = tanhf(acc + bfu(qr2_b[j2]));
      cp *= cosf(qin) * cosf(bfu(q_weights[j2]));
      qo[j2] = cp;
    }
    const uint32* hrow0 = (const uint32*)h_s;
    const uint32* cw = (const uint32*)clf_w + tid * 66;
    float acc = 0.f;
    #pragma unroll 4
    for (int k2 = 0; k2 < 64; ++k2) {
      float ha, hb, wa, wb;
      bf2(hrow0[k2], ha, hb); bf2(cw[k2], wa, wb);
      acc += ha * wa + hb * wb;
    }
    #pragma unroll
    for (int d = 0; d < 4; ++d) acc += qo[d] * bfu(clf_w[tid * 132 + 128 + d]);
    acc += bfu(clf_b[tid]);
    if (f32m) ((float*)out)[b * 10 + tid] = acc;
    else      ((ushort_t*)out)[b * 10 + tid] = f2bf(acc);
  }
}

extern "C" void kernel_launch(void* const* d_in, const int* in_sizes, int n_in,
                              void* d_out, int out_size, void* d_ws, size_t ws_size,
                              hipStream_t stream) {
  // Canonicalize the 23 weight arrays (inputs 1..23) into ws as bf16.
  WPack p;
  unsigned cur = 0;
  for (int i = 0; i < 23; ++i) {
    p.src[i] = d_in[i + 1];
    p.off[i] = cur;
    p.n[i]   = (unsigned)in_sizes[i + 1];
    cur += (p.n[i] + 7u) & ~7u;   // 16B-aligned segments
  }
  ushort_t* wsb = (ushort_t*)d_ws;
  const ushort_t* x = (const ushort_t*)d_in[0];

  canon<<<dim3(128), dim3(256), 0, stream>>>(p, x, wsb);

  int B = out_size / 10;   // output is (B, 10)
  vit_fused<<<dim3(B), dim3(256), 0, stream>>>(
      x,
      wsb + p.off[0],  wsb + p.off[1],  wsb + p.off[2],  wsb + p.off[3],
      wsb + p.off[4],  wsb + p.off[5],  wsb + p.off[6],  wsb + p.off[7],
      wsb + p.off[8],  wsb + p.off[9],  wsb + p.off[10], wsb + p.off[11],
      wsb + p.off[12], wsb + p.off[13], wsb + p.off[14], wsb + p.off[15],
      wsb + p.off[16], wsb + p.off[17], wsb + p.off[18], wsb + p.off[19],
      wsb + p.off[20], wsb + p.off[21], wsb + p.off[22],
      d_out);
}

// Round 4
// 1118.759 us; speedup vs baseline: 12.6854x; 12.6854x over previous
//
#include <hip/hip_runtime.h>

typedef unsigned short ushort_t;
typedef unsigned int   uint32;
typedef short s16x8 __attribute__((ext_vector_type(8)));
typedef float f32x4 __attribute__((ext_vector_type(4)));

#define HS   136   // h stride (272B rows: 16B aligned, 2-way banks)
#define KS   40    // k/q tile stride
#define VS   104   // vT stride
#define PS   104   // P stride
#define OS   136   // O stride
#define FS   264   // ff1out stride
#define EPS_ 1e-5f
#define SCALE_ 0.17677669529663687f  // 1/sqrt(32)

// big[] element offsets
#define Q_OFF  0        // q [5][16][40]  = 3200
#define K_OFF  3200     // k [80][40]     = 3200
#define VT_OFF 6400     // vT [32][104]   = 3328
#define P_OFF  9728     // P [4][16][104] = 6656
#define O_OFF  16384    // O [80][136]    = 10880
#define BIG_N  27264    // 54528 B ; + h 21760 B = 76288 B LDS total

#define MFMA16(a,b,c) __builtin_amdgcn_mfma_f32_16x16x32_bf16((a),(b),(c),0,0,0)

__device__ __forceinline__ float bfu(ushort_t u) {
  union { uint32 i; float f; } c; c.i = ((uint32)u) << 16; return c.f;
}
__device__ __forceinline__ void bf2(uint32 u, float& a, float& b) {
  union { uint32 i; float f; } c0, c1;
  c0.i = u << 16; c1.i = u & 0xffff0000u; a = c0.f; b = c1.f;
}
__device__ __forceinline__ ushort_t f2bf(float f) {
  union { float f; uint32 i; } c; c.f = f;
  uint32 r = c.i + 0x7fffu + ((c.i >> 16) & 1u);
  return (ushort_t)(r >> 16);
}

// Statistical dtype sniff on the first 256 ushorts of x (fp32 vs bf16 buffer).
__device__ bool sniff_f32(const ushort_t* x) {
  int insane = 0, zeros = 0;
  for (int i = 0; i < 256; ++i) {
    ushort_t u = x[i];
    int e = (u >> 7) & 0xFF;
    if (u == 0) zeros++;
    else if (e == 0xFF || e < 0x60) insane++;
  }
  return (insane >= 16) || (zeros >= 64);
}

struct WPack {
  const void* src[23];
  unsigned    off[23];
  unsigned    n[23];
};

__global__ __launch_bounds__(256) void canon(WPack p, const ushort_t* x, ushort_t* dst) {
  const bool f32 = sniff_f32(x);
  const int gid = blockIdx.x * blockDim.x + threadIdx.x;
  const int gsz = gridDim.x * blockDim.x;
  for (int a = 0; a < 23; ++a) {
    unsigned n = p.n[a];
    ushort_t* d = dst + p.off[a];
    if (f32) {
      const float* s = (const float*)p.src[a];
      for (unsigned i = gid; i < n; i += gsz) d[i] = f2bf(s[i]);
    } else {
      const ushort_t* s = (const ushort_t*)p.src[a];
      for (unsigned i = gid; i < n; i += gsz) d[i] = s[i];
    }
  }
}

__global__ __launch_bounds__(256)
void vit_fused(const ushort_t* __restrict__ x,          // original x (dtype sniffed)
               const ushort_t* __restrict__ patch_w,    // all weights canonical bf16
               const ushort_t* __restrict__ patch_b,
               const ushort_t* __restrict__ cls_token,
               const ushort_t* __restrict__ pos_embed,
               const ushort_t* __restrict__ qkv_w,
               const ushort_t* __restrict__ qkv_b,
               const ushort_t* __restrict__ out_w,
               const ushort_t* __restrict__ out_b,
               const ushort_t* __restrict__ ln1_s,
               const ushort_t* __restrict__ ln1_b,
               const ushort_t* __restrict__ ln2_s,
               const ushort_t* __restrict__ ln2_b,
               const ushort_t* __restrict__ ff1_w,
               const ushort_t* __restrict__ ff1_b,
               const ushort_t* __restrict__ ff2_w,
               const ushort_t* __restrict__ ff2_b,
               const ushort_t* __restrict__ qr1_w,
               const ushort_t* __restrict__ qr1_b,
               const ushort_t* __restrict__ qr2_w,
               const ushort_t* __restrict__ qr2_b,
               const ushort_t* __restrict__ q_weights,
               const ushort_t* __restrict__ clf_w,
               const ushort_t* __restrict__ clf_b,
               void* __restrict__ out)
{
  __shared__ __align__(16) ushort_t h_s[80 * HS];   // 21760 B
  __shared__ __align__(16) ushort_t big[BIG_N];     // 54528 B

  const int tid  = threadIdx.x;
  const int wid  = tid >> 6;
  const int lane = tid & 63;
  const int lr   = lane & 15;   // tile row/col index
  const int lq   = lane >> 4;   // quad 0..3
  const int b    = blockIdx.x;
  const bool f32m = sniff_f32(x);

  ushort_t* qE  = big + Q_OFF;
  ushort_t* kE  = big + K_OFF;
  ushort_t* vTE = big + VT_OFF;
  ushort_t* pE  = big + P_OFF;
  ushort_t* oE  = big + O_OFF;
  ushort_t* fE  = big;          // ff1out [80][264] overlays attn buffers

  // ---------------- stage x + patch_w into big ----------------
  uint32* bx = (uint32*)big;
  if (f32m) {
    const float* xf = (const float*)x + (size_t)b * 3072;
    for (int i = tid; i < 1536; i += 256) {
      uint32 lo = f2bf(xf[2 * i]);
      uint32 hi = f2bf(xf[2 * i + 1]);
      bx[i] = lo | (hi << 16);
    }
  } else {
    const uint32* xb = (const uint32*)x + (size_t)b * 1536;
    for (int i = tid; i < 1536; i += 256) bx[i] = xb[i];
  }
  {
    const uint32* pw = (const uint32*)patch_w;
    for (int i = tid; i < 3072; i += 256) bx[1536 + i] = pw[i];
  }
  __syncthreads();

  // ---------------- patch embed (VALU, small) ----------------
  #pragma unroll 1
  for (int it = 0; it < 32; ++it) {
    int idx = tid + 256 * it;
    int p = idx >> 7, d = idx & 127;
    int pi = p >> 3, pj = p & 7;
    float acc = 0.f;
    #pragma unroll
    for (int c = 0; c < 3; ++c) {
      #pragma unroll
      for (int py = 0; py < 4; ++py) {
        const uint32* xr = bx + ((c * 1024 + (pi * 4 + py) * 32 + pj * 4) >> 1);
        const uint32* wr = bx + 1536 + ((d * 48 + c * 16 + py * 4) >> 1);
        #pragma unroll
        for (int q2 = 0; q2 < 2; ++q2) {
          float xa, xb2, wa, wb;
          bf2(xr[q2], xa, xb2); bf2(wr[q2], wa, wb);
          acc += xa * wa + xb2 * wb;
        }
      }
    }
    acc += bfu(patch_b[d]) + bfu(pos_embed[(1 + p) * 128 + d]);
    h_s[(1 + p) * HS + d] = f2bf(acc);
  }
  if (tid < 128) h_s[tid] = f2bf(bfu(cls_token[tid]) + bfu(pos_embed[tid]));
  for (int i = tid; i < 15 * HS; i += 256) h_s[65 * HS + i] = 0;   // zero pad rows 65-79

  // ---------------- transformer layers ----------------
  #pragma unroll 1
  for (int il = 0; il < 4; ++il) {
    __syncthreads();   // h complete; big free (prev ffE reads done)

    // zero vT pad cols 80..95 and P pad cols 80..95 (PV reads up to col 95)
    for (int i = tid; i < 512; i += 256)
      vTE[(i >> 4) * VS + 80 + (i & 15)] = 0;
    for (int i = tid; i < 1024; i += 256)
      pE[(i >> 8) * (16 * PS) + ((i >> 4) & 15) * PS + 80 + (i & 15)] = 0;

    const ushort_t* Wqkv = qkv_w + (size_t)il * 384 * 128;
    const ushort_t* Bqkv = qkv_b + il * 384;

    #pragma unroll 1
    for (int ih = 0; ih < 4; ++ih) {
      // ---- k/v/q tiles: 15 units = (type 0..2) x (m-tile 0..4)
      #pragma unroll 1
      for (int u = wid; u < 15; u += 4) {
        int ty = u % 3, mt = u / 3, m0 = mt * 16;
        int rb = (ty == 2 ? 0 : (ty == 0 ? 128 : 256)) + ih * 32;
        const ushort_t* W    = Wqkv + (size_t)rb * 128;
        const ushort_t* bias = Bqkv + rb;
        #pragma unroll
        for (int nt = 0; nt < 2; ++nt) {
          int n0 = nt * 16;
          float bv = bfu(bias[n0 + lr]);
          f32x4 acc = {bv, bv, bv, bv};
          #pragma unroll
          for (int kc = 0; kc < 4; ++kc) {
            s16x8 a  = *(const s16x8*)&h_s[(m0 + lr) * HS + kc * 32 + lq * 8];
            s16x8 bb = *(const s16x8*)&W[(n0 + lr) * 128 + kc * 32 + lq * 8];
            acc = MFMA16(a, bb, acc);
          }
          if (ty == 0) {         // k[token][dim]
            #pragma unroll
            for (int i = 0; i < 4; ++i)
              kE[(m0 + lq * 4 + i) * KS + n0 + lr] = f2bf(acc[i]);
          } else if (ty == 1) {  // vT[dim][token], pack 4 tokens
            uint32 w0 = (uint32)f2bf(acc[0]) | ((uint32)f2bf(acc[1]) << 16);
            uint32 w1 = (uint32)f2bf(acc[2]) | ((uint32)f2bf(acc[3]) << 16);
            uint32* dst = (uint32*)&vTE[(n0 + lr) * VS + m0 + lq * 4];
            dst[0] = w0; dst[1] = w1;
          } else {               // q[mtile][row][dim], pre-scaled
            #pragma unroll
            for (int i = 0; i < 4; ++i)
              qE[mt * 640 + (lq * 4 + i) * KS + n0 + lr] = f2bf(acc[i] * SCALE_);
          }
        }
      }
      __syncthreads();   // k/vT/q ready

      // ---- scores + softmax + PV (wave w: m-tiles w, w+4)
      #pragma unroll 1
      for (int mt = wid; mt < 5; mt += 4) {
        int m0 = mt * 16;
        f32x4 S[5];
        s16x8 aq = *(const s16x8*)&qE[mt * 640 + lr * KS + lq * 8];
        #pragma unroll
        for (int jt = 0; jt < 5; ++jt) {
          f32x4 z = {0.f, 0.f, 0.f, 0.f};
          s16x8 bb = *(const s16x8*)&kE[(jt * 16 + lr) * KS + lq * 8];
          S[jt] = MFMA16(aq, bb, z);
        }
        // softmax over j (rows r = lq*4+i, cols j = jt*16+lr); mask j>64
        float mx[4] = {-1e30f, -1e30f, -1e30f, -1e30f};
        #pragma unroll
        for (int jt = 0; jt < 5; ++jt)
          #pragma unroll
          for (int i = 0; i < 4; ++i) {
            float s = S[jt][i];
            if (jt == 4 && lr > 0) s = -1e30f;
            S[jt][i] = s;
            mx[i] = fmaxf(mx[i], s);
          }
        #pragma unroll
        for (int off = 1; off < 16; off <<= 1)
          #pragma unroll
          for (int i = 0; i < 4; ++i)
            mx[i] = fmaxf(mx[i], __shfl_xor(mx[i], off));
        float sm[4] = {0.f, 0.f, 0.f, 0.f};
        #pragma unroll
        for (int jt = 0; jt < 5; ++jt)
          #pragma unroll
          for (int i = 0; i < 4; ++i) {
            float pv = __expf(S[jt][i] - mx[i]);
            S[jt][i] = pv; sm[i] += pv;
          }
        #pragma unroll
        for (int off = 1; off < 16; off <<= 1)
          #pragma unroll
          for (int i = 0; i < 4; ++i)
            sm[i] += __shfl_xor(sm[i], off);
        float inv[4];
        #pragma unroll
        for (int i = 0; i < 4; ++i) inv[i] = 1.f / sm[i];
        ushort_t* Pw = pE + wid * (16 * PS);
        #pragma unroll
        for (int jt = 0; jt < 5; ++jt)
          #pragma unroll
          for (int i = 0; i < 4; ++i)
            Pw[(lq * 4 + i) * PS + jt * 16 + lr] = f2bf(S[jt][i] * inv[i]);

        // PV: O[m][d] = P @ V  (B = vT rows = dims)
        #pragma unroll
        for (int nt = 0; nt < 2; ++nt) {
          int n0 = nt * 16;
          f32x4 acc = {0.f, 0.f, 0.f, 0.f};
          #pragma unroll
          for (int kc = 0; kc < 3; ++kc) {
            s16x8 a  = *(const s16x8*)&Pw[lr * PS + kc * 32 + lq * 8];
            s16x8 bb = *(const s16x8*)&vTE[(n0 + lr) * VS + kc * 32 + lq * 8];
            acc = MFMA16(a, bb, acc);
          }
          #pragma unroll
          for (int i = 0; i < 4; ++i)
            oE[(m0 + lq * 4 + i) * OS + ih * 32 + n0 + lr] = f2bf(acc[i]);
        }
      }
      __syncthreads();   // protect k/vT/q for next head
    } // heads

    // ---- out-proj + residual + LN1 (wave-private m-tiles)
    {
      const ushort_t* Wo = out_w + (size_t)il * 128 * 128;
      #pragma unroll 1
      for (int mt = wid; mt < 5; mt += 4) {
        int m0 = mt * 16;
        s16x8 a[4];
        #pragma unroll
        for (int kc = 0; kc < 4; ++kc)
          a[kc] = *(const s16x8*)&oE[(m0 + lr) * OS + kc * 32 + lq * 8];
        float xr[8][4];
        #pragma unroll
        for (int nt = 0; nt < 8; ++nt) {
          float bv = bfu(out_b[il * 128 + nt * 16 + lr]);
          f32x4 acc = {bv, bv, bv, bv};
          #pragma unroll
          for (int kc = 0; kc < 4; ++kc) {
            s16x8 bb = *(const s16x8*)&Wo[(nt * 16 + lr) * 128 + kc * 32 + lq * 8];
            acc = MFMA16(a[kc], bb, acc);
          }
          #pragma unroll
          for (int i = 0; i < 4; ++i)
            xr[nt][i] = acc[i] + bfu(h_s[(m0 + lq * 4 + i) * HS + nt * 16 + lr]);
        }
        float s[4] = {0,0,0,0}, ss[4] = {0,0,0,0};
        #pragma unroll
        for (int nt = 0; nt < 8; ++nt)
          #pragma unroll
          for (int i = 0; i < 4; ++i) { s[i] += xr[nt][i]; ss[i] += xr[nt][i] * xr[nt][i]; }
        #pragma unroll
        for (int off = 1; off < 16; off <<= 1)
          #pragma unroll
          for (int i = 0; i < 4; ++i) {
            s[i]  += __shfl_xor(s[i], off);
            ss[i] += __shfl_xor(ss[i], off);
          }
        float mean[4], inv[4];
        #pragma unroll
        for (int i = 0; i < 4; ++i) {
          mean[i] = s[i] * (1.f / 128.f);
          inv[i]  = rsqrtf(fmaxf(ss[i] * (1.f / 128.f) - mean[i] * mean[i], 0.f) + EPS_);
        }
        #pragma unroll
        for (int nt = 0; nt < 8; ++nt) {
          float g  = bfu(ln1_s[il * 128 + nt * 16 + lr]);
          float be = bfu(ln1_b[il * 128 + nt * 16 + lr]);
          #pragma unroll
          for (int i = 0; i < 4; ++i)
            h_s[(m0 + lq * 4 + i) * HS + nt * 16 + lr] =
                f2bf((xr[nt][i] - mean[i]) * inv[i] * g + be);
        }
      }
    }
    __syncthreads();   // h(LN1) ready; O dead -> fE usable

    // ---- ff1 (relu) -> fE
    {
      const ushort_t* W1 = ff1_w + (size_t)il * 256 * 128;
      #pragma unroll 1
      for (int mt = 0; mt < 5; ++mt) {
        int m0 = mt * 16;
        s16x8 a[4];
        #pragma unroll
        for (int kc = 0; kc < 4; ++kc)
          a[kc] = *(const s16x8*)&h_s[(m0 + lr) * HS + kc * 32 + lq * 8];
        #pragma unroll 1
        for (int nt = wid; nt < 16; nt += 4) {
          int n0 = nt * 16;
          float bv = bfu(ff1_b[il * 256 + n0 + lr]);
          f32x4 acc = {bv, bv, bv, bv};
          #pragma unroll
          for (int kc = 0; kc < 4; ++kc) {
            s16x8 bb = *(const s16x8*)&W1[(n0 + lr) * 128 + kc * 32 + lq * 8];
            acc = MFMA16(a[kc], bb, acc);
          }
          #pragma unroll
          for (int i = 0; i < 4; ++i)
            fE[(m0 + lq * 4 + i) * FS + n0 + lr] = f2bf(fmaxf(acc[i], 0.f));
        }
      }
    }
    __syncthreads();   // fE ready

    // ---- ff2 + residual + LN2
    {
      const ushort_t* W2 = ff2_w + (size_t)il * 128 * 256;
      #pragma unroll 1
      for (int mt = wid; mt < 5; mt += 4) {
        int m0 = mt * 16;
        s16x8 a[8];
        #pragma unroll
        for (int kc = 0; kc < 8; ++kc)
          a[kc] = *(const s16x8*)&fE[(m0 + lr) * FS + kc * 32 + lq * 8];
        float xr[8][4];
        #pragma unroll
        for (int nt = 0; nt < 8; ++nt) {
          float bv = bfu(ff2_b[il * 128 + nt * 16 + lr]);
          f32x4 acc = {bv, bv, bv, bv};
          #pragma unroll
          for (int kc = 0; kc < 8; ++kc) {
            s16x8 bb = *(const s16x8*)&W2[(nt * 16 + lr) * 256 + kc * 32 + lq * 8];
            acc = MFMA16(a[kc], bb, acc);
          }
          #pragma unroll
          for (int i = 0; i < 4; ++i)
            xr[nt][i] = acc[i] + bfu(h_s[(m0 + lq * 4 + i) * HS + nt * 16 + lr]);
        }
        float s[4] = {0,0,0,0}, ss[4] = {0,0,0,0};
        #pragma unroll
        for (int nt = 0; nt < 8; ++nt)
          #pragma unroll
          for (int i = 0; i < 4; ++i) { s[i] += xr[nt][i]; ss[i] += xr[nt][i] * xr[nt][i]; }
        #pragma unroll
        for (int off = 1; off < 16; off <<= 1)
          #pragma unroll
          for (int i = 0; i < 4; ++i) {
            s[i]  += __shfl_xor(s[i], off);
            ss[i] += __shfl_xor(ss[i], off);
          }
        float mean[4], inv[4];
        #pragma unroll
        for (int i = 0; i < 4; ++i) {
          mean[i] = s[i] * (1.f / 128.f);
          inv[i]  = rsqrtf(fmaxf(ss[i] * (1.f / 128.f) - mean[i] * mean[i], 0.f) + EPS_);
        }
        #pragma unroll
        for (int nt = 0; nt < 8; ++nt) {
          float g  = bfu(ln2_s[il * 128 + nt * 16 + lr]);
          float be = bfu(ln2_b[il * 128 + nt * 16 + lr]);
          #pragma unroll
          for (int i = 0; i < 4; ++i)
            h_s[(m0 + lq * 4 + i) * HS + nt * 16 + lr] =
                f2bf((xr[nt][i] - mean[i]) * inv[i] * g + be);
        }
      }
    }
  } // layers

  // ---------------- head (VALU, tiny) ----------------
  __syncthreads();
  float* scr = (float*)big;
  {
    int j = tid & 31;
    const uint32* hrow0 = (const uint32*)h_s;
    const uint32* w = (const uint32*)qr1_w + j * 64;
    float acc = 0.f;
    #pragma unroll 4
    for (int k2 = 0; k2 < 64; ++k2) {
      float ha, hb, wa, wb;
      bf2(hrow0[k2], ha, hb); bf2(w[k2], wa, wb);
      acc += ha * wa + hb * wb;
    }
    float u = fmaxf(acc + bfu(qr1_b[j]), 0.f);
    if (tid < 32) scr[tid] = u;
  }
  __syncthreads();
  if (tid < 10) {
    float qo[4]; float cp = 1.f;
    #pragma unroll
    for (int j2 = 0; j2 < 4; ++j2) {
      float acc = 0.f;
      #pragma unroll
      for (int k = 0; k < 32; ++k) acc += scr[k] * bfu(qr2_w[j2 * 32 + k]);
      float qin = tanhf(acc + bfu(qr2_b[j2]));
      cp *= cosf(qin) * cosf(bfu(q_weights[j2]));
      qo[j2] = cp;
    }
    const uint32* hrow0 = (const uint32*)h_s;
    const uint32* cw = (const uint32*)clf_w + tid * 66;   // clf row stride 132
    float acc = 0.f;
    #pragma unroll 4
    for (int k2 = 0; k2 < 64; ++k2) {
      float ha, hb, wa, wb;
      bf2(hrow0[k2], ha, hb); bf2(cw[k2], wa, wb);
      acc += ha * wa + hb * wb;
    }
    #pragma unroll
    for (int d = 0; d < 4; ++d) acc += qo[d] * bfu(clf_w[tid * 132 + 128 + d]);
    acc += bfu(clf_b[tid]);
    if (f32m) ((float*)out)[b * 10 + tid] = acc;
    else      ((ushort_t*)out)[b * 10 + tid] = f2bf(acc);
  }
}

extern "C" void kernel_launch(void* const* d_in, const int* in_sizes, int n_in,
                              void* d_out, int out_size, void* d_ws, size_t ws_size,
                              hipStream_t stream) {
  WPack p;
  unsigned cur = 0;
  for (int i = 0; i < 23; ++i) {
    p.src[i] = d_in[i + 1];
    p.off[i] = cur;
    p.n[i]   = (unsigned)in_sizes[i + 1];
    cur += (p.n[i] + 7u) & ~7u;
  }
  ushort_t* wsb = (ushort_t*)d_ws;
  const ushort_t* x = (const ushort_t*)d_in[0];

  canon<<<dim3(128), dim3(256), 0, stream>>>(p, x, wsb);

  int B = out_size / 10;
  vit_fused<<<dim3(B), dim3(256), 0, stream>>>(
      x,
      wsb + p.off[0],  wsb + p.off[1],  wsb + p.off[2],  wsb + p.off[3],
      wsb + p.off[4],  wsb + p.off[5],  wsb + p.off[6],  wsb + p.off[7],
      wsb + p.off[8],  wsb + p.off[9],  wsb + p.off[10], wsb + p.off[11],
      wsb + p.off[12], wsb + p.off[13], wsb + p.off[14], wsb + p.off[15],
      wsb + p.off[16], wsb + p.off[17], wsb + p.off[18], wsb + p.off[19],
      wsb + p.off[20], wsb + p.off[21], wsb + p.off[22],
      d_out);
}

// Round 6
// 984.379 us; speedup vs baseline: 14.4171x; 1.1365x over previous
//
#include <hip/hip_runtime.h>

typedef unsigned short ushort_t;
typedef unsigned int   uint32;
typedef short s16x8 __attribute__((ext_vector_type(8)));
typedef float f32x4 __attribute__((ext_vector_type(4)));

#define HS    136    // h stride (272B rows, 16B aligned)
#define QOF   0      // q  [5][16][40]  = 3200 elems
#define KOF   3200   // k  [80][40]     = 3200
#define VOF   6400   // vT [32][96]     = 3072
#define POF   9472   // P slices [4][16][96] = 6144 (bounce overlays slice @stride 40)
#define SBF   15616  // mt4 LN stats: 4 waves x 16 rows x float2 = 512B (256 elems)
#define BIGN  15872  // big total elems (31744 B); + h 21760 B = 53504 B LDS
#define EPS_  1e-5f
#define SCALE_ 0.17677669529663687f  // 1/sqrt(32)

#define MFMA16(a,b,c) __builtin_amdgcn_mfma_f32_16x16x32_bf16((a),(b),(c),0,0,0)

__device__ __forceinline__ float bfu(ushort_t u) {
  union { uint32 i; float f; } c; c.i = ((uint32)u) << 16; return c.f;
}
__device__ __forceinline__ void bf2(uint32 u, float& a, float& b) {
  union { uint32 i; float f; } c0, c1;
  c0.i = u << 16; c1.i = u & 0xffff0000u; a = c0.f; b = c1.f;
}
__device__ __forceinline__ ushort_t f2bf(float f) {
  union { float f; uint32 i; } c; c.f = f;
  uint32 r = c.i + 0x7fffu + ((c.i >> 16) & 1u);
  return (ushort_t)(r >> 16);
}

// Statistical dtype sniff on the first 256 ushorts of x (fp32 vs bf16 buffer).
__device__ bool sniff_f32(const ushort_t* x) {
  int insane = 0, zeros = 0;
  for (int i = 0; i < 256; ++i) {
    ushort_t u = x[i];
    int e = (u >> 7) & 0xFF;
    if (u == 0) zeros++;
    else if (e == 0xFF || e < 0x60) insane++;
  }
  return (insane >= 16) || (zeros >= 64);
}

struct WPack {
  const void* src[23];
  unsigned    off[23];
  unsigned    n[23];
};

__global__ __launch_bounds__(256) void canon(WPack p, const ushort_t* x, ushort_t* dst,
                                             int* flagOut) {
  const bool f32 = sniff_f32(x);
  const int gid = blockIdx.x * blockDim.x + threadIdx.x;
  const int gsz = gridDim.x * blockDim.x;
  for (int a = 0; a < 23; ++a) {
    unsigned n = p.n[a];
    ushort_t* d = dst + p.off[a];
    if (f32) {
      const float* s = (const float*)p.src[a];
      for (unsigned i = gid; i < n; i += gsz) d[i] = f2bf(s[i]);
    } else {
      const ushort_t* s = (const ushort_t*)p.src[a];
      for (unsigned i = gid; i < n; i += gsz) d[i] = s[i];
    }
  }
  if (blockIdx.x == 0 && threadIdx.x == 0) *flagOut = f32 ? 1 : 0;
}

__global__ __launch_bounds__(256, 3)   // 3 waves/EU -> VGPR<=170, 12 waves/CU w/ 3 blocks
void vit_fused(const ushort_t* __restrict__ x,
               const ushort_t* __restrict__ patch_w,
               const ushort_t* __restrict__ patch_b,
               const ushort_t* __restrict__ cls_token,
               const ushort_t* __restrict__ pos_embed,
               const ushort_t* __restrict__ qkv_w,
               const ushort_t* __restrict__ qkv_b,
               const ushort_t* __restrict__ out_w,
               const ushort_t* __restrict__ out_b,
               const ushort_t* __restrict__ ln1_s,
               const ushort_t* __restrict__ ln1_b,
               const ushort_t* __restrict__ ln2_s,
               const ushort_t* __restrict__ ln2_b,
               const ushort_t* __restrict__ ff1_w,
               const ushort_t* __restrict__ ff1_b,
               const ushort_t* __restrict__ ff2_w,
               const ushort_t* __restrict__ ff2_b,
               const ushort_t* __restrict__ qr1_w,
               const ushort_t* __restrict__ qr1_b,
               const ushort_t* __restrict__ qr2_w,
               const ushort_t* __restrict__ qr2_b,
               const ushort_t* __restrict__ q_weights,
               const ushort_t* __restrict__ clf_w,
               const ushort_t* __restrict__ clf_b,
               const int* __restrict__ flag,
               void* __restrict__ out)
{
  __shared__ __align__(16) ushort_t h_s[80 * HS];   // 21760 B
  __shared__ __align__(16) ushort_t big[BIGN];      // 31744 B

  const int tid  = threadIdx.x;
  const int wid  = tid >> 6;
  const int lane = tid & 63;
  const int lr   = lane & 15;
  const int lq   = lane >> 4;
  const int b    = blockIdx.x;
  const bool f32m = (*flag != 0);

  // ---------------- stage x + patch_w into big ----------------
  uint32* bx = (uint32*)big;
  if (f32m) {
    const float* xf = (const float*)x + (size_t)b * 3072;
    for (int i = tid; i < 1536; i += 256) {
      uint32 lo = f2bf(xf[2 * i]);
      uint32 hi = f2bf(xf[2 * i + 1]);
      bx[i] = lo | (hi << 16);
    }
  } else {
    const uint32* xb = (const uint32*)x + (size_t)b * 1536;
    for (int i = tid; i < 1536; i += 256) bx[i] = xb[i];
  }
  {
    const uint32* pw = (const uint32*)patch_w;
    for (int i = tid; i < 3072; i += 256) bx[1536 + i] = pw[i];
  }
  __syncthreads();

  // ---------------- patch embed (scalar, ~1% of MACs) ----------------
  #pragma unroll 1
  for (int it = 0; it < 32; ++it) {
    int idx = tid + 256 * it;
    int p = idx >> 7, d = idx & 127;
    int pi = p >> 3, pj = p & 7;
    float acc = 0.f;
    #pragma unroll
    for (int c = 0; c < 3; ++c) {
      #pragma unroll
      for (int py = 0; py < 4; ++py) {
        const uint32* xr = bx + ((c * 1024 + (pi * 4 + py) * 32 + pj * 4) >> 1);
        const uint32* wr = bx + 1536 + ((d * 48 + c * 16 + py * 4) >> 1);
        #pragma unroll
        for (int q2 = 0; q2 < 2; ++q2) {
          float xa, xb2, wa, wb;
          bf2(xr[q2], xa, xb2); bf2(wr[q2], wa, wb);
          acc += xa * wa + xb2 * wb;
        }
      }
    }
    acc += bfu(patch_b[d]) + bfu(pos_embed[(1 + p) * 128 + d]);
    h_s[(1 + p) * HS + d] = f2bf(acc);
  }
  if (tid < 128) h_s[tid] = f2bf(bfu(cls_token[tid]) + bfu(pos_embed[tid]));
  for (int i = tid; i < 15 * HS; i += 256) h_s[65 * HS + i] = 0;   // zero pad rows 65..79

  // ---------------- transformer layers ----------------
  #pragma unroll 1
  for (int il = 0; il < 4; ++il) {
    __syncthreads();   // h ready; big free

    // CRITICAL (R5 NaN fix): zero vT pad token-cols 80..95. PV reads them
    // (kc=2 spans tokens 64..95); layer-0 LDS is uninitialized (can decode
    // as inf/NaN -> 0*inf=NaN), later layers hold stale FF data. Ordered
    // before the first "kvq ready" barrier below.
    for (int i = tid; i < 512; i += 256)
      big[VOF + (i >> 4) * 96 + 80 + (i & 15)] = 0;

    const ushort_t* Wqkv = qkv_w + (size_t)il * 384 * 128;
    const ushort_t* Bqkv = qkv_b + il * 384;
    const ushort_t* Wo   = out_w + (size_t)il * 128 * 128;

    // persistent out-proj accumulators (bias-initialized)
    f32x4 opAcc[8];
    #pragma unroll
    for (int nt = 0; nt < 8; ++nt) {
      float bv = bfu(out_b[il * 128 + nt * 16 + lr]);
      opAcc[nt] = (f32x4){bv, bv, bv, bv};
    }
    f32x4 opAcc4[2];
    #pragma unroll
    for (int j = 0; j < 2; ++j) {
      float bv = bfu(out_b[il * 128 + (2 * wid + j) * 16 + lr]);
      opAcc4[j] = (f32x4){bv, bv, bv, bv};
    }

    auto attn_mt = [&](int mt, bool own, int ih) {
      ushort_t* Pw = big + POF + wid * 1536;
      // scores: S = (q*scale) @ k^T
      s16x8 aq = *(const s16x8*)&big[QOF + mt * 640 + lr * 40 + lq * 8];
      f32x4 S[5];
      #pragma unroll
      for (int jt = 0; jt < 5; ++jt) {
        s16x8 bb = *(const s16x8*)&big[KOF + (jt * 16 + lr) * 40 + lq * 8];
        f32x4 z = {0.f, 0.f, 0.f, 0.f};
        S[jt] = MFMA16(aq, bb, z);
      }
      float mx[4] = {-1e30f, -1e30f, -1e30f, -1e30f};
      #pragma unroll
      for (int jt = 0; jt < 5; ++jt)
        #pragma unroll
        for (int i = 0; i < 4; ++i) {
          float s = S[jt][i];
          if (jt == 4 && lr > 0) s = -1e30f;   // mask key tokens 65..79
          S[jt][i] = s;
          mx[i] = fmaxf(mx[i], s);
        }
      #pragma unroll
      for (int off = 1; off < 16; off <<= 1)
        #pragma unroll
        for (int i = 0; i < 4; ++i) mx[i] = fmaxf(mx[i], __shfl_xor(mx[i], off));
      float sm[4] = {0.f, 0.f, 0.f, 0.f};
      #pragma unroll
      for (int jt = 0; jt < 5; ++jt)
        #pragma unroll
        for (int i = 0; i < 4; ++i) {
          float pv = __expf(S[jt][i] - mx[i]);
          S[jt][i] = pv; sm[i] += pv;
        }
      #pragma unroll
      for (int off = 1; off < 16; off <<= 1)
        #pragma unroll
        for (int i = 0; i < 4; ++i) sm[i] += __shfl_xor(sm[i], off);
      float inv[4];
      #pragma unroll
      for (int i = 0; i < 4; ++i) inv[i] = 1.f / sm[i];
      #pragma unroll
      for (int i = 0; i < 4; ++i) {
        #pragma unroll
        for (int jt = 0; jt < 5; ++jt)
          Pw[(lq * 4 + i) * 96 + jt * 16 + lr] = f2bf(S[jt][i] * inv[i]);
        Pw[(lq * 4 + i) * 96 + 80 + lr] = 0;   // exact-zero P cols 80..95
      }
      // PV: O-tile = P @ V (vT rows = dims)
      f32x4 ov[2];
      #pragma unroll
      for (int n2 = 0; n2 < 2; ++n2) {
        f32x4 acc = {0.f, 0.f, 0.f, 0.f};
        #pragma unroll
        for (int kc = 0; kc < 3; ++kc) {
          s16x8 a  = *(const s16x8*)&Pw[lr * 96 + kc * 32 + lq * 8];
          s16x8 bb = *(const s16x8*)&big[VOF + (n2 * 16 + lr) * 96 + kc * 32 + lq * 8];
          acc = MFMA16(a, bb, acc);
        }
        ov[n2] = acc;
      }
      // bounce O-tile (C-layout) -> A-layout via own P slice (stride 40)
      ushort_t* bn = big + POF + wid * 1536;
      #pragma unroll
      for (int n2 = 0; n2 < 2; ++n2)
        #pragma unroll
        for (int i = 0; i < 4; ++i)
          bn[(lq * 4 + i) * 40 + n2 * 16 + lr] = f2bf(ov[n2][i]);
      if (own) {
        s16x8 a = *(const s16x8*)&bn[lr * 40 + lq * 8];
        #pragma unroll
        for (int nt = 0; nt < 8; ++nt) {
          s16x8 bb = *(const s16x8*)&Wo[(nt * 16 + lr) * 128 + ih * 32 + lq * 8];
          opAcc[nt] = MFMA16(a, bb, opAcc[nt]);
        }
      }
    };

    #pragma unroll 1
    for (int ih = 0; ih < 4; ++ih) {
      // ---- k/v/q tiles for this head: 15 units over 4 waves
      #pragma unroll 1
      for (int u = wid; u < 15; u += 4) {
        int ty = u % 3, mt = u / 3, m0 = mt * 16;
        int rb = (ty == 0 ? 128 : (ty == 1 ? 256 : 0)) + ih * 32;
        const ushort_t* W    = Wqkv + (size_t)rb * 128;
        const ushort_t* bias = Bqkv + rb;
        #pragma unroll
        for (int nt = 0; nt < 2; ++nt) {
          int n0 = nt * 16;
          float bv = bfu(bias[n0 + lr]);
          f32x4 acc = {bv, bv, bv, bv};
          #pragma unroll
          for (int kc = 0; kc < 4; ++kc) {
            s16x8 a  = *(const s16x8*)&h_s[(m0 + lr) * HS + kc * 32 + lq * 8];
            s16x8 bb = *(const s16x8*)&W[(n0 + lr) * 128 + kc * 32 + lq * 8];
            acc = MFMA16(a, bb, acc);
          }
          if (ty == 0) {            // k[token][dim32]
            #pragma unroll
            for (int i = 0; i < 4; ++i)
              big[KOF + (m0 + lq * 4 + i) * 40 + n0 + lr] = f2bf(acc[i]);
          } else if (ty == 1) {     // vT[dim32][token], packed 4 tokens
            uint32 w0 = (uint32)f2bf(acc[0]) | ((uint32)f2bf(acc[1]) << 16);
            uint32 w1 = (uint32)f2bf(acc[2]) | ((uint32)f2bf(acc[3]) << 16);
            uint32* dst = (uint32*)&big[VOF + (n0 + lr) * 96 + m0 + lq * 4];
            dst[0] = w0; dst[1] = w1;
          } else {                  // q[token][dim32], pre-scaled
            #pragma unroll
            for (int i = 0; i < 4; ++i)
              big[QOF + mt * 640 + (lq * 4 + i) * 40 + n0 + lr] = f2bf(acc[i] * SCALE_);
          }
        }
      }
      __syncthreads();   // kvq (and vT pad zeros) visible

      attn_mt(wid, true, ih);
      if (wid == 3) attn_mt(4, false, ih);
      __syncthreads();   // PV done; mt4 bounce (slice 3) ready; kvq bufs reusable

      // shared mt4 out-proj accumulation (2 n-tiles per wave)
      {
        s16x8 a4 = *(const s16x8*)&big[POF + 3 * 1536 + lr * 40 + lq * 8];
        #pragma unroll
        for (int j = 0; j < 2; ++j) {
          int nt = 2 * wid + j;
          s16x8 bb = *(const s16x8*)&Wo[(nt * 16 + lr) * 128 + ih * 32 + lq * 8];
          opAcc4[j] = MFMA16(a4, bb, opAcc4[j]);
        }
      }
    } // heads

    // ---- LN1 epilogue: own m-tile (wave-local)
    {
      int m0 = wid * 16;
      float s[4] = {0, 0, 0, 0}, ss[4] = {0, 0, 0, 0};
      #pragma unroll
      for (int nt = 0; nt < 8; ++nt)
        #pragma unroll
        for (int i = 0; i < 4; ++i) {
          float r = opAcc[nt][i] + bfu(h_s[(m0 + lq * 4 + i) * HS + nt * 16 + lr]);
          opAcc[nt][i] = r; s[i] += r; ss[i] += r * r;
        }
      #pragma unroll
      for (int off = 1; off < 16; off <<= 1)
        #pragma unroll
        for (int i = 0; i < 4; ++i) {
          s[i]  += __shfl_xor(s[i], off);
          ss[i] += __shfl_xor(ss[i], off);
        }
      float mean[4], inv[4];
      #pragma unroll
      for (int i = 0; i < 4; ++i) {
        mean[i] = s[i] * (1.f / 128.f);
        inv[i]  = rsqrtf(fmaxf(ss[i] * (1.f / 128.f) - mean[i] * mean[i], 0.f) + EPS_);
      }
      #pragma unroll
      for (int nt = 0; nt < 8; ++nt) {
        float g  = bfu(ln1_s[il * 128 + nt * 16 + lr]);
        float be = bfu(ln1_b[il * 128 + nt * 16 + lr]);
        #pragma unroll
        for (int i = 0; i < 4; ++i)
          h_s[(m0 + lq * 4 + i) * HS + nt * 16 + lr] =
              f2bf((opAcc[nt][i] - mean[i]) * inv[i] * g + be);
      }
      // mt4 partial stats (this wave's 32 cols)
      float s4[4] = {0, 0, 0, 0}, ss4[4] = {0, 0, 0, 0};
      #pragma unroll
      for (int j = 0; j < 2; ++j)
        #pragma unroll
        for (int i = 0; i < 4; ++i) {
          float r = opAcc4[j][i] +
                    bfu(h_s[(64 + lq * 4 + i) * HS + (2 * wid + j) * 16 + lr]);
          opAcc4[j][i] = r; s4[i] += r; ss4[i] += r * r;
        }
      #pragma unroll
      for (int off = 1; off < 16; off <<= 1)
        #pragma unroll
        for (int i = 0; i < 4; ++i) {
          s4[i]  += __shfl_xor(s4[i], off);
          ss4[i] += __shfl_xor(ss4[i], off);
        }
      float2* st = (float2*)&big[SBF];
      if (lr == 0) {
        #pragma unroll
        for (int i = 0; i < 4; ++i) {
          float2 v; v.x = s4[i]; v.y = ss4[i];
          st[wid * 16 + lq * 4 + i] = v;
        }
      }
    }
    __syncthreads();   // stats ready
    {
      float2* st = (float2*)&big[SBF];
      #pragma unroll
      for (int i = 0; i < 4; ++i) {
        int row = lq * 4 + i;
        float S_ = 0.f, SS_ = 0.f;
        #pragma unroll
        for (int w = 0; w < 4; ++w) { float2 v = st[w * 16 + row]; S_ += v.x; SS_ += v.y; }
        float mean = S_ * (1.f / 128.f);
        float inv  = rsqrtf(fmaxf(SS_ * (1.f / 128.f) - mean * mean, 0.f) + EPS_);
        #pragma unroll
        for (int j = 0; j < 2; ++j) {
          int c = (2 * wid + j) * 16 + lr;
          float g  = bfu(ln1_s[il * 128 + c]);
          float be = bfu(ln1_b[il * 128 + c]);
          h_s[(64 + row) * HS + c] = f2bf((opAcc4[j][i] - mean) * inv * g + be);
        }
      }
    }
    __syncthreads();   // h fully LN1'd; attn region free for ff slices

    // ---- FF fused per wave: ff1(relu) -> ff2 in two k-halves, private slice
    {
      const ushort_t* W1 = ff1_w + (size_t)il * 256 * 128;
      const ushort_t* W2 = ff2_w + (size_t)il * 128 * 256;
      ushort_t* fsl = big + wid * 2176;   // [16][136] private
      int nmt = (wid == 3) ? 2 : 1;
      #pragma unroll 1
      for (int q2 = 0; q2 < nmt; ++q2) {
        int mt = (q2 == 0) ? wid : 4;
        int m0 = mt * 16;
        s16x8 ha[4];
        #pragma unroll
        for (int kc = 0; kc < 4; ++kc)
          ha[kc] = *(const s16x8*)&h_s[(m0 + lr) * HS + kc * 32 + lq * 8];
        f32x4 acc2[8];
        #pragma unroll
        for (int nt = 0; nt < 8; ++nt) {
          float bv = bfu(ff2_b[il * 128 + nt * 16 + lr]);
          acc2[nt] = (f32x4){bv, bv, bv, bv};
        }
        #pragma unroll 1
        for (int half = 0; half < 2; ++half) {
          #pragma unroll 1
          for (int n8 = 0; n8 < 8; ++n8) {
            int ng = half * 8 + n8;
            float bv = bfu(ff1_b[il * 256 + ng * 16 + lr]);
            f32x4 acc = {bv, bv, bv, bv};
            #pragma unroll
            for (int kc = 0; kc < 4; ++kc) {
              s16x8 bb = *(const s16x8*)&W1[(ng * 16 + lr) * 128 + kc * 32 + lq * 8];
              acc = MFMA16(ha[kc], bb, acc);
            }
            #pragma unroll
            for (int i = 0; i < 4; ++i)
              fsl[(lq * 4 + i) * 136 + n8 * 16 + lr] = f2bf(fmaxf(acc[i], 0.f));
          }
          #pragma unroll
          for (int kc = 0; kc < 4; ++kc) {
            s16x8 a2 = *(const s16x8*)&fsl[lr * 136 + kc * 32 + lq * 8];
            #pragma unroll
            for (int nt = 0; nt < 8; ++nt) {
              s16x8 bb = *(const s16x8*)&W2[(nt * 16 + lr) * 256 + half * 128 + kc * 32 + lq * 8];
              acc2[nt] = MFMA16(a2, bb, acc2[nt]);
            }
          }
        }
        // LN2 epilogue (wave-local)
        float s[4] = {0, 0, 0, 0}, ss[4] = {0, 0, 0, 0};
        #pragma unroll
        for (int nt = 0; nt < 8; ++nt)
          #pragma unroll
          for (int i = 0; i < 4; ++i) {
            float r = acc2[nt][i] + bfu(h_s[(m0 + lq * 4 + i) * HS + nt * 16 + lr]);
            acc2[nt][i] = r; s[i] += r; ss[i] += r * r;
          }
        #pragma unroll
        for (int off = 1; off < 16; off <<= 1)
          #pragma unroll
          for (int i = 0; i < 4; ++i) {
            s[i]  += __shfl_xor(s[i], off);
            ss[i] += __shfl_xor(ss[i], off);
          }
        float mean[4], inv[4];
        #pragma unroll
        for (int i = 0; i < 4; ++i) {
          mean[i] = s[i] * (1.f / 128.f);
          inv[i]  = rsqrtf(fmaxf(ss[i] * (1.f / 128.f) - mean[i] * mean[i], 0.f) + EPS_);
        }
        #pragma unroll
        for (int nt = 0; nt < 8; ++nt) {
          float g  = bfu(ln2_s[il * 128 + nt * 16 + lr]);
          float be = bfu(ln2_b[il * 128 + nt * 16 + lr]);
          #pragma unroll
          for (int i = 0; i < 4; ++i)
            h_s[(m0 + lq * 4 + i) * HS + nt * 16 + lr] =
                f2bf((acc2[nt][i] - mean[i]) * inv[i] * g + be);
        }
      }
    }
  } // layers

  // ---------------- head (tiny scalar) ----------------
  __syncthreads();
  float* scr = (float*)big;
  {
    int j = tid & 31;
    const uint32* hrow0 = (const uint32*)h_s;
    const uint32* w = (const uint32*)qr1_w + j * 64;
    float acc = 0.f;
    #pragma unroll 4
    for (int k2 = 0; k2 < 64; ++k2) {
      float ha, hb, wa, wb;
      bf2(hrow0[k2], ha, hb); bf2(w[k2], wa, wb);
      acc += ha * wa + hb * wb;
    }
    float u = fmaxf(acc + bfu(qr1_b[j]), 0.f);
    if (tid < 32) scr[tid] = u;
  }
  __syncthreads();
  if (tid < 10) {
    float qo[4]; float cp = 1.f;
    #pragma unroll
    for (int j2 = 0; j2 < 4; ++j2) {
      float acc = 0.f;
      #pragma unroll
      for (int k = 0; k < 32; ++k) acc += scr[k] * bfu(qr2_w[j2 * 32 + k]);
      float qin = tanhf(acc + bfu(qr2_b[j2]));
      cp *= cosf(qin) * cosf(bfu(q_weights[j2]));
      qo[j2] = cp;
    }
    const uint32* hrow0 = (const uint32*)h_s;
    const uint32* cw = (const uint32*)clf_w + tid * 66;   // clf row stride 132 elems
    float acc = 0.f;
    #pragma unroll 4
    for (int k2 = 0; k2 < 64; ++k2) {
      float ha, hb, wa, wb;
      bf2(hrow0[k2], ha, hb); bf2(cw[k2], wa, wb);
      acc += ha * wa + hb * wb;
    }
    #pragma unroll
    for (int d = 0; d < 4; ++d) acc += qo[d] * bfu(clf_w[tid * 132 + 128 + d]);
    acc += bfu(clf_b[tid]);
    if (f32m) ((float*)out)[b * 10 + tid] = acc;
    else      ((ushort_t*)out)[b * 10 + tid] = f2bf(acc);
  }
}

extern "C" void kernel_launch(void* const* d_in, const int* in_sizes, int n_in,
                              void* d_out, int out_size, void* d_ws, size_t ws_size,
                              hipStream_t stream) {
  WPack p;
  unsigned cur = 0;
  for (int i = 0; i < 23; ++i) {
    p.src[i] = d_in[i + 1];
    p.off[i] = cur;
    p.n[i]   = (unsigned)in_sizes[i + 1];
    cur += (p.n[i] + 7u) & ~7u;
  }
  ushort_t* wsb = (ushort_t*)d_ws;
  unsigned flag_off = (cur * 2 + 3u) & ~3u;          // byte offset, 4B aligned
  int* flagp = (int*)((char*)d_ws + flag_off);
  const ushort_t* x = (const ushort_t*)d_in[0];

  canon<<<dim3(128), dim3(256), 0, stream>>>(p, x, wsb, flagp);

  int B = out_size / 10;
  vit_fused<<<dim3(B), dim3(256), 0, stream>>>(
      x,
      wsb + p.off[0],  wsb + p.off[1],  wsb + p.off[2],  wsb + p.off[3],
      wsb + p.off[4],  wsb + p.off[5],  wsb + p.off[6],  wsb + p.off[7],
      wsb + p.off[8],  wsb + p.off[9],  wsb + p.off[10], wsb + p.off[11],
      wsb + p.off[12], wsb + p.off[13], wsb + p.off[14], wsb + p.off[15],
      wsb + p.off[16], wsb + p.off[17], wsb + p.off[18], wsb + p.off[19],
      wsb + p.off[20], wsb + p.off[21], wsb + p.off[22],
      flagp, d_out);
}

// Round 7
// 818.341 us; speedup vs baseline: 17.3423x; 1.2029x over previous
//
#include <hip/hip_runtime.h>

typedef unsigned short ushort_t;
typedef unsigned int   uint32;
typedef short s16x8 __attribute__((ext_vector_type(8)));
typedef float f32x4 __attribute__((ext_vector_type(4)));

#define HS    136    // h stride (272B rows: 16B aligned, 4-dw bank rotation -> conflict-free)
#define KOF   0      // kE [80][136] = 10880 elems (also FF fsl overlay: wid*2176)
#define VOF   10880  // vT [128][96] = 12288 elems
#define PWOF  23168  // per-wave [16][96] slices (P / q-bounce / O-bounce): 4*1536
#define BIGN  29312  // big = 58624 B; + h 21760 B = 80384 B LDS -> 2 blocks/CU
#define EPS_  1e-5f
#define SCALE_ 0.17677669529663687f  // 1/sqrt(32)

#define MFMA16(a,b,c) __builtin_amdgcn_mfma_f32_16x16x32_bf16((a),(b),(c),0,0,0)

__device__ __forceinline__ float bfu(ushort_t u) {
  union { uint32 i; float f; } c; c.i = ((uint32)u) << 16; return c.f;
}
__device__ __forceinline__ void bf2(uint32 u, float& a, float& b) {
  union { uint32 i; float f; } c0, c1;
  c0.i = u << 16; c1.i = u & 0xffff0000u; a = c0.f; b = c1.f;
}
__device__ __forceinline__ ushort_t f2bf(float f) {
  union { float f; uint32 i; } c; c.f = f;
  uint32 r = c.i + 0x7fffu + ((c.i >> 16) & 1u);
  return (ushort_t)(r >> 16);
}

// Statistical dtype sniff on the first 256 ushorts of x (fp32 vs bf16 buffer).
__device__ bool sniff_f32(const ushort_t* x) {
  int insane = 0, zeros = 0;
  for (int i = 0; i < 256; ++i) {
    ushort_t u = x[i];
    int e = (u >> 7) & 0xFF;
    if (u == 0) zeros++;
    else if (e == 0xFF || e < 0x60) insane++;
  }
  return (insane >= 16) || (zeros >= 64);
}

struct WPack {
  const void* src[23];
  unsigned    off[23];
  unsigned    n[23];
};

__global__ __launch_bounds__(256) void canon(WPack p, const ushort_t* x, ushort_t* dst,
                                             int* flagOut) {
  const bool f32 = sniff_f32(x);
  const int gid = blockIdx.x * blockDim.x + threadIdx.x;
  const int gsz = gridDim.x * blockDim.x;
  for (int a = 0; a < 23; ++a) {
    unsigned n = p.n[a];
    ushort_t* d = dst + p.off[a];
    if (f32) {
      const float* s = (const float*)p.src[a];
      for (unsigned i = gid; i < n; i += gsz) d[i] = f2bf(s[i]);
    } else {
      const ushort_t* s = (const ushort_t*)p.src[a];
      for (unsigned i = gid; i < n; i += gsz) d[i] = s[i];
    }
  }
  if (blockIdx.x == 0 && threadIdx.x == 0) *flagOut = f32 ? 1 : 0;
}

__global__ __launch_bounds__(256, 2)   // 2 blocks/CU (LDS-capped) = 8 waves/CU
void vit_fused(const ushort_t* __restrict__ x,
               const ushort_t* __restrict__ patch_w,
               const ushort_t* __restrict__ patch_b,
               const ushort_t* __restrict__ cls_token,
               const ushort_t* __restrict__ pos_embed,
               const ushort_t* __restrict__ qkv_w,
               const ushort_t* __restrict__ qkv_b,
               const ushort_t* __restrict__ out_w,
               const ushort_t* __restrict__ out_b,
               const ushort_t* __restrict__ ln1_s,
               const ushort_t* __restrict__ ln1_b,
               const ushort_t* __restrict__ ln2_s,
               const ushort_t* __restrict__ ln2_b,
               const ushort_t* __restrict__ ff1_w,
               const ushort_t* __restrict__ ff1_b,
               const ushort_t* __restrict__ ff2_w,
               const ushort_t* __restrict__ ff2_b,
               const ushort_t* __restrict__ qr1_w,
               const ushort_t* __restrict__ qr1_b,
               const ushort_t* __restrict__ qr2_w,
               const ushort_t* __restrict__ qr2_b,
               const ushort_t* __restrict__ q_weights,
               const ushort_t* __restrict__ clf_w,
               const ushort_t* __restrict__ clf_b,
               const int* __restrict__ flag,
               void* __restrict__ out)
{
  __shared__ __align__(16) ushort_t h_s[80 * HS];   // 21760 B
  __shared__ __align__(16) ushort_t big[BIGN];      // 58624 B

  const int tid  = threadIdx.x;
  const int wid  = tid >> 6;
  const int lane = tid & 63;
  const int lr   = lane & 15;
  const int lq   = lane >> 4;
  const int b    = blockIdx.x;
  const bool f32m = (*flag != 0);
  const int nOwn = (wid == 3) ? 2 : 1;   // wave3 owns mt3+mt4 in attention/q

  // ---------------- stage x + patch_w into big ----------------
  uint32* bx = (uint32*)big;
  if (f32m) {
    const float* xf = (const float*)x + (size_t)b * 3072;
    for (int i = tid; i < 1536; i += 256) {
      uint32 lo = f2bf(xf[2 * i]);
      uint32 hi = f2bf(xf[2 * i + 1]);
      bx[i] = lo | (hi << 16);
    }
  } else {
    const uint32* xb = (const uint32*)x + (size_t)b * 1536;
    for (int i = tid; i < 1536; i += 256) bx[i] = xb[i];
  }
  {
    const uint32* pw = (const uint32*)patch_w;
    for (int i = tid; i < 3072; i += 256) bx[1536 + i] = pw[i];
  }
  __syncthreads();

  // ---------------- patch embed (scalar, ~1% of MACs) ----------------
  #pragma unroll 1
  for (int it = 0; it < 32; ++it) {
    int idx = tid + 256 * it;
    int p = idx >> 7, d = idx & 127;
    int pi = p >> 3, pj = p & 7;
    float acc = 0.f;
    #pragma unroll
    for (int c = 0; c < 3; ++c) {
      #pragma unroll
      for (int py = 0; py < 4; ++py) {
        const uint32* xr = bx + ((c * 1024 + (pi * 4 + py) * 32 + pj * 4) >> 1);
        const uint32* wr = bx + 1536 + ((d * 48 + c * 16 + py * 4) >> 1);
        #pragma unroll
        for (int q2 = 0; q2 < 2; ++q2) {
          float xa, xb2, wa, wb;
          bf2(xr[q2], xa, xb2); bf2(wr[q2], wa, wb);
          acc += xa * wa + xb2 * wb;
        }
      }
    }
    acc += bfu(patch_b[d]) + bfu(pos_embed[(1 + p) * 128 + d]);
    h_s[(1 + p) * HS + d] = f2bf(acc);
  }
  if (tid < 128) h_s[tid] = f2bf(bfu(cls_token[tid]) + bfu(pos_embed[tid]));
  for (int i = tid; i < 15 * HS; i += 256) h_s[65 * HS + i] = 0;   // zero pad rows 65..79

  // kv-unit ranges: compensate wave3's 2x attention / wave0's 2x FF
  const int st0 = (wid == 0) ? 0 : (wid == 1) ? 2 : (wid == 2) ? 35 : 68;
  const int st1 = (wid == 0) ? 2 : (wid == 1) ? 35 : (wid == 2) ? 68 : 80;

  // ---------------- transformer layers (3 barriers each) ----------------
  #pragma unroll 1
  for (int il = 0; il < 4; ++il) {
    __syncthreads();   // h stable (LN2/init); big free (prev FF fsl dead)

    // zero vT pad token-cols 80..95 (PV kc=2 reads tokens 64..95; stale/uninit otherwise)
    for (int i = tid; i < 2048; i += 256)
      big[VOF + (i >> 4) * 96 + 80 + (i & 15)] = 0;

    const ushort_t* Wqkv = qkv_w + (size_t)il * 384 * 128;
    const ushort_t* Bqkv = qkv_b + il * 384;
    const ushort_t* Wo   = out_w + (size_t)il * 128 * 128;

    // ---- phase 1: k_all / vT_all (shared) + q for own m-tiles (registers)
    #pragma unroll 1
    for (int u = st0; u < st1; ++u) {
      int ty = u & 1, r = u >> 1;
      int mt = r >> 3, nt = r & 7;
      int m0 = mt * 16;
      int rb = (ty ? 256 : 128) + nt * 16;
      float bv = bfu(Bqkv[rb + lr]);
      f32x4 acc = {bv, bv, bv, bv};
      #pragma unroll
      for (int kc = 0; kc < 4; ++kc) {
        s16x8 a  = *(const s16x8*)&h_s[(m0 + lr) * HS + kc * 32 + lq * 8];
        s16x8 bb = *(const s16x8*)&Wqkv[(rb + lr) * 128 + kc * 32 + lq * 8];
        acc = MFMA16(a, bb, acc);
      }
      if (!ty) {   // k[token][dim], stride 136
        #pragma unroll
        for (int i = 0; i < 4; ++i)
          big[KOF + (m0 + lq * 4 + i) * 136 + nt * 16 + lr] = f2bf(acc[i]);
      } else {     // vT[dim][token], stride 96, pack 4 tokens
        uint32 w0 = (uint32)f2bf(acc[0]) | ((uint32)f2bf(acc[1]) << 16);
        uint32 w1 = (uint32)f2bf(acc[2]) | ((uint32)f2bf(acc[3]) << 16);
        uint32* dst = (uint32*)&big[VOF + (nt * 16 + lr) * 96 + m0 + lq * 4];
        dst[0] = w0; dst[1] = w1;
      }
    }
    s16x8 qa[2][4];
    {
      ushort_t* bw = big + PWOF + wid * 1536;   // private bounce, stride 40
      #pragma unroll 1
      for (int s = 0; s < nOwn; ++s) {
        int mt = (s == 0) ? wid : 4;
        int m0 = mt * 16;
        s16x8 ha[4];
        #pragma unroll
        for (int kc = 0; kc < 4; ++kc)
          ha[kc] = *(const s16x8*)&h_s[(m0 + lr) * HS + kc * 32 + lq * 8];
        #pragma unroll 1
        for (int ih = 0; ih < 4; ++ih) {
          #pragma unroll
          for (int n2 = 0; n2 < 2; ++n2) {
            int rb = ih * 32 + n2 * 16;   // q rows 0..127
            float bv = bfu(Bqkv[rb + lr]);
            f32x4 acc = {bv, bv, bv, bv};
            #pragma unroll
            for (int kc = 0; kc < 4; ++kc) {
              s16x8 bb = *(const s16x8*)&Wqkv[(rb + lr) * 128 + kc * 32 + lq * 8];
              acc = MFMA16(ha[kc], bb, acc);
            }
            #pragma unroll
            for (int i = 0; i < 4; ++i)
              bw[(lq * 4 + i) * 40 + n2 * 16 + lr] = f2bf(acc[i] * SCALE_);
          }
          qa[s][ih] = *(const s16x8*)&bw[lr * 40 + lq * 8];
        }
      }
    }
    __syncthreads();   // kE / vT ready

    // ---- phase 2: attention + out-proj + LN1, fully wave-private per own mt
    #pragma unroll 1
    for (int s = 0; s < nOwn; ++s) {
      int mt = (s == 0) ? wid : 4;
      int m0 = mt * 16;
      ushort_t* Pw = big + PWOF + wid * 1536;
      f32x4 opA[8];
      #pragma unroll
      for (int nt = 0; nt < 8; ++nt) {
        float bv = bfu(out_b[il * 128 + nt * 16 + lr]);
        opA[nt] = (f32x4){bv, bv, bv, bv};
      }
      #pragma unroll 1
      for (int ih = 0; ih < 4; ++ih) {
        s16x8 aq = qa[s][ih];
        f32x4 S[5];
        #pragma unroll
        for (int jt = 0; jt < 5; ++jt) {
          s16x8 bb = *(const s16x8*)&big[KOF + (jt * 16 + lr) * 136 + ih * 32 + lq * 8];
          f32x4 z = {0.f, 0.f, 0.f, 0.f};
          S[jt] = MFMA16(aq, bb, z);
        }
        float mx[4] = {-1e30f, -1e30f, -1e30f, -1e30f};
        #pragma unroll
        for (int jt = 0; jt < 5; ++jt)
          #pragma unroll
          for (int i = 0; i < 4; ++i) {
            float sv = S[jt][i];
            if (jt == 4 && lr > 0) sv = -1e30f;   // mask key tokens 65..79
            S[jt][i] = sv;
            mx[i] = fmaxf(mx[i], sv);
          }
        #pragma unroll
        for (int off = 1; off < 16; off <<= 1)
          #pragma unroll
          for (int i = 0; i < 4; ++i) mx[i] = fmaxf(mx[i], __shfl_xor(mx[i], off));
        float sm[4] = {0.f, 0.f, 0.f, 0.f};
        #pragma unroll
        for (int jt = 0; jt < 5; ++jt)
          #pragma unroll
          for (int i = 0; i < 4; ++i) {
            float pv = __expf(S[jt][i] - mx[i]);
            S[jt][i] = pv; sm[i] += pv;
          }
        #pragma unroll
        for (int off = 1; off < 16; off <<= 1)
          #pragma unroll
          for (int i = 0; i < 4; ++i) sm[i] += __shfl_xor(sm[i], off);
        float inv[4];
        #pragma unroll
        for (int i = 0; i < 4; ++i) inv[i] = 1.f / sm[i];
        #pragma unroll
        for (int i = 0; i < 4; ++i) {
          #pragma unroll
          for (int jt = 0; jt < 5; ++jt)
            Pw[(lq * 4 + i) * 96 + jt * 16 + lr] = f2bf(S[jt][i] * inv[i]);
          Pw[(lq * 4 + i) * 96 + 80 + lr] = 0;   // exact-zero P cols 80..95
        }
        // PV
        f32x4 ov[2];
        #pragma unroll
        for (int n2 = 0; n2 < 2; ++n2) {
          f32x4 acc = {0.f, 0.f, 0.f, 0.f};
          #pragma unroll
          for (int kc = 0; kc < 3; ++kc) {
            s16x8 a  = *(const s16x8*)&Pw[lr * 96 + kc * 32 + lq * 8];
            s16x8 bb = *(const s16x8*)&big[VOF + (ih * 32 + n2 * 16 + lr) * 96 + kc * 32 + lq * 8];
            acc = MFMA16(a, bb, acc);
          }
          ov[n2] = acc;
        }
        // O bounce (stride-40 overlay on Pw; same-wave in-order LDS) -> A-frag -> out-proj
        #pragma unroll
        for (int n2 = 0; n2 < 2; ++n2)
          #pragma unroll
          for (int i = 0; i < 4; ++i)
            Pw[(lq * 4 + i) * 40 + n2 * 16 + lr] = f2bf(ov[n2][i]);
        s16x8 ao = *(const s16x8*)&Pw[lr * 40 + lq * 8];
        #pragma unroll
        for (int nt = 0; nt < 8; ++nt) {
          s16x8 bb = *(const s16x8*)&Wo[(nt * 16 + lr) * 128 + ih * 32 + lq * 8];
          opA[nt] = MFMA16(ao, bb, opA[nt]);
        }
      } // heads

      // LN1 for this mt (wave-local; pad rows are finite garbage, never poison real rows)
      float sv[4] = {0, 0, 0, 0}, ssv[4] = {0, 0, 0, 0};
      #pragma unroll
      for (int nt = 0; nt < 8; ++nt)
        #pragma unroll
        for (int i = 0; i < 4; ++i) {
          float r = opA[nt][i] + bfu(h_s[(m0 + lq * 4 + i) * HS + nt * 16 + lr]);
          opA[nt][i] = r; sv[i] += r; ssv[i] += r * r;
        }
      #pragma unroll
      for (int off = 1; off < 16; off <<= 1)
        #pragma unroll
        for (int i = 0; i < 4; ++i) {
          sv[i]  += __shfl_xor(sv[i], off);
          ssv[i] += __shfl_xor(ssv[i], off);
        }
      float mean[4], inv[4];
      #pragma unroll
      for (int i = 0; i < 4; ++i) {
        mean[i] = sv[i] * (1.f / 128.f);
        inv[i]  = rsqrtf(fmaxf(ssv[i] * (1.f / 128.f) - mean[i] * mean[i], 0.f) + EPS_);
      }
      #pragma unroll
      for (int nt = 0; nt < 8; ++nt) {
        float g  = bfu(ln1_s[il * 128 + nt * 16 + lr]);
        float be = bfu(ln1_b[il * 128 + nt * 16 + lr]);
        #pragma unroll
        for (int i = 0; i < 4; ++i)
          h_s[(m0 + lq * 4 + i) * HS + nt * 16 + lr] =
              f2bf((opA[nt][i] - mean[i]) * inv[i] * g + be);
      }
    } // own mts
    __syncthreads();   // h(LN1) visible; kE dead -> fsl overlay

    // ---- phase 3: FF (ff1 relu -> ff2) + LN2; wave0 also does mt4
    {
      const ushort_t* W1 = ff1_w + (size_t)il * 256 * 128;
      const ushort_t* W2 = ff2_w + (size_t)il * 128 * 256;
      ushort_t* fsl = big + KOF + wid * 2176;   // [16][136] private (kE region)
      int nFF = (wid == 0) ? 2 : 1;
      #pragma unroll 1
      for (int s = 0; s < nFF; ++s) {
        int mt = (s == 0) ? wid : 4;
        int m0 = mt * 16;
        s16x8 ha[4];
        #pragma unroll
        for (int kc = 0; kc < 4; ++kc)
          ha[kc] = *(const s16x8*)&h_s[(m0 + lr) * HS + kc * 32 + lq * 8];
        f32x4 acc2[8];
        #pragma unroll
        for (int nt = 0; nt < 8; ++nt) {
          float bv = bfu(ff2_b[il * 128 + nt * 16 + lr]);
          acc2[nt] = (f32x4){bv, bv, bv, bv};
        }
        #pragma unroll 1
        for (int half = 0; half < 2; ++half) {
          #pragma unroll 1
          for (int n8 = 0; n8 < 8; ++n8) {
            int ng = half * 8 + n8;
            float bv = bfu(ff1_b[il * 256 + ng * 16 + lr]);
            f32x4 acc = {bv, bv, bv, bv};
            #pragma unroll
            for (int kc = 0; kc < 4; ++kc) {
              s16x8 bb = *(const s16x8*)&W1[(ng * 16 + lr) * 128 + kc * 32 + lq * 8];
              acc = MFMA16(ha[kc], bb, acc);
            }
            #pragma unroll
            for (int i = 0; i < 4; ++i)
              fsl[(lq * 4 + i) * 136 + n8 * 16 + lr] = f2bf(fmaxf(acc[i], 0.f));
          }
          #pragma unroll
          for (int kc = 0; kc < 4; ++kc) {
            s16x8 a2 = *(const s16x8*)&fsl[lr * 136 + kc * 32 + lq * 8];
            #pragma unroll
            for (int nt = 0; nt < 8; ++nt) {
              s16x8 bb = *(const s16x8*)&W2[(nt * 16 + lr) * 256 + half * 128 + kc * 32 + lq * 8];
              acc2[nt] = MFMA16(a2, bb, acc2[nt]);
            }
          }
        }
        // LN2 (wave-local)
        float sv[4] = {0, 0, 0, 0}, ssv[4] = {0, 0, 0, 0};
        #pragma unroll
        for (int nt = 0; nt < 8; ++nt)
          #pragma unroll
          for (int i = 0; i < 4; ++i) {
            float r = acc2[nt][i] + bfu(h_s[(m0 + lq * 4 + i) * HS + nt * 16 + lr]);
            acc2[nt][i] = r; sv[i] += r; ssv[i] += r * r;
          }
        #pragma unroll
        for (int off = 1; off < 16; off <<= 1)
          #pragma unroll
          for (int i = 0; i < 4; ++i) {
            sv[i]  += __shfl_xor(sv[i], off);
            ssv[i] += __shfl_xor(ssv[i], off);
          }
        float mean[4], inv[4];
        #pragma unroll
        for (int i = 0; i < 4; ++i) {
          mean[i] = sv[i] * (1.f / 128.f);
          inv[i]  = rsqrtf(fmaxf(ssv[i] * (1.f / 128.f) - mean[i] * mean[i], 0.f) + EPS_);
        }
        #pragma unroll
        for (int nt = 0; nt < 8; ++nt) {
          float g  = bfu(ln2_s[il * 128 + nt * 16 + lr]);
          float be = bfu(ln2_b[il * 128 + nt * 16 + lr]);
          #pragma unroll
          for (int i = 0; i < 4; ++i)
            h_s[(m0 + lq * 4 + i) * HS + nt * 16 + lr] =
                f2bf((acc2[nt][i] - mean[i]) * inv[i] * g + be);
        }
      }
    }
  } // layers

  // ---------------- head (tiny scalar) ----------------
  __syncthreads();
  float* scr = (float*)big;
  {
    int j = tid & 31;
    const uint32* hrow0 = (const uint32*)h_s;
    const uint32* w = (const uint32*)qr1_w + j * 64;
    float acc = 0.f;
    #pragma unroll 4
    for (int k2 = 0; k2 < 64; ++k2) {
      float ha, hb, wa, wb;
      bf2(hrow0[k2], ha, hb); bf2(w[k2], wa, wb);
      acc += ha * wa + hb * wb;
    }
    float u = fmaxf(acc + bfu(qr1_b[j]), 0.f);
    if (tid < 32) scr[tid] = u;
  }
  __syncthreads();
  if (tid < 10) {
    float qo[4]; float cp = 1.f;
    #pragma unroll
    for (int j2 = 0; j2 < 4; ++j2) {
      float acc = 0.f;
      #pragma unroll
      for (int k = 0; k < 32; ++k) acc += scr[k] * bfu(qr2_w[j2 * 32 + k]);
      float qin = tanhf(acc + bfu(qr2_b[j2]));
      cp *= cosf(qin) * cosf(bfu(q_weights[j2]));
      qo[j2] = cp;
    }
    const uint32* hrow0 = (const uint32*)h_s;
    const uint32* cw = (const uint32*)clf_w + tid * 66;   // clf row stride 132 elems
    float acc = 0.f;
    #pragma unroll 4
    for (int k2 = 0; k2 < 64; ++k2) {
      float ha, hb, wa, wb;
      bf2(hrow0[k2], ha, hb); bf2(cw[k2], wa, wb);
      acc += ha * wa + hb * wb;
    }
    #pragma unroll
    for (int d = 0; d < 4; ++d) acc += qo[d] * bfu(clf_w[tid * 132 + 128 + d]);
    acc += bfu(clf_b[tid]);
    if (f32m) ((float*)out)[b * 10 + tid] = acc;
    else      ((ushort_t*)out)[b * 10 + tid] = f2bf(acc);
  }
}

extern "C" void kernel_launch(void* const* d_in, const int* in_sizes, int n_in,
                              void* d_out, int out_size, void* d_ws, size_t ws_size,
                              hipStream_t stream) {
  WPack p;
  unsigned cur = 0;
  for (int i = 0; i < 23; ++i) {
    p.src[i] = d_in[i + 1];
    p.off[i] = cur;
    p.n[i]   = (unsigned)in_sizes[i + 1];
    cur += (p.n[i] + 7u) & ~7u;
  }
  ushort_t* wsb = (ushort_t*)d_ws;
  unsigned flag_off = (cur * 2 + 3u) & ~3u;          // byte offset, 4B aligned
  int* flagp = (int*)((char*)d_ws + flag_off);
  const ushort_t* x = (const ushort_t*)d_in[0];

  canon<<<dim3(128), dim3(256), 0, stream>>>(p, x, wsb, flagp);

  int B = out_size / 10;
  vit_fused<<<dim3(B), dim3(256), 0, stream>>>(
      x,
      wsb + p.off[0],  wsb + p.off[1],  wsb + p.off[2],  wsb + p.off[3],
      wsb + p.off[4],  wsb + p.off[5],  wsb + p.off[6],  wsb + p.off[7],
      wsb + p.off[8],  wsb + p.off[9],  wsb + p.off[10], wsb + p.off[11],
      wsb + p.off[12], wsb + p.off[13], wsb + p.off[14], wsb + p.off[15],
      wsb + p.off[16], wsb + p.off[17], wsb + p.off[18], wsb + p.off[19],
      wsb + p.off[20], wsb + p.off[21], wsb + p.off[22],
      flagp, d_out);
}